// Round 9
// baseline (214.001 us; speedup 1.0000x reference)
//
#include <hip/hip_runtime.h>
#include <math.h>

// GCN 2-layer, MI355X. Round 9: R8 confirmed int LDS atomics are 2x fp32
// (b2 91->44.7us). Now halve b2's atomic count: pack both fixed-point
// components into one ds_add_u64 with per-addend 2^31 bias (carry-exact);
// reduce-side recovers cnt = round(1/dinv^2)-1 and unbiases. Partial layout
// byte-identical (BSZ u64 == 2*BSZ i32) so ws NEED unchanged.

#define NBK     13
#define BSHIFT  13
#define BSZ     8192            // nodes per bucket
#define CAP     540672          // per-bucket edge capacity = 524288 + 16384 (23 sigma)
#define R1REP   40              // replicas/bucket for deg & agg1 (grid 520)
#define R2REP   20              // replicas/bucket for agg2 (grid 260)
#define ABLK    512             // threads for agg kernels
#define BBLK    512             // threads for bucketize
#define ACHUNK  8192            // edges per bucketize block (16/thread)

#define FXS     1048576.0f          // 2^20
#define FXI     9.5367431640625e-7f // 2^-20

typedef unsigned uv4 __attribute__((ext_vector_type(4)));
typedef unsigned long long u64;

__device__ __forceinline__ uv4 ntload_u4(const unsigned* p) {
    return __builtin_nontemporal_load((const uv4*)p);
}

__device__ __forceinline__ u64 pack_fx(float2 v) {
    int q0 = __float2int_rn(v.x * FXS);
    int q1 = __float2int_rn(v.y * FXS);
    return ((u64)(unsigned)q1 << 32) + (u64)(unsigned)q0 + 0x80000000ull;
}

// ---------------- fast path kernels ----------------

// R5-style bucketize (verified fast): per-lane LDS atomics on 13 counters,
// LDS stage, coalesced copy-out.
__global__ __launch_bounds__(BBLK) void bucketize_kernel(
        const int* __restrict__ src, const int* __restrict__ dst,
        unsigned* __restrict__ cursors, unsigned* __restrict__ ebuf, int E) {
    __shared__ unsigned stage[ACHUNK];          // 32 KB
    __shared__ unsigned cnt[NBK], gbase[NBK], loff[NBK], run[NBK];
    int t = threadIdx.x;
    if (t < NBK) { cnt[t] = 0; run[t] = 0; }
    __syncthreads();
    int e0 = blockIdx.x * ACHUNK;
    unsigned pk[16];
    int bb[16];
    if (e0 + ACHUNK <= E) {
        const int4* s4 = (const int4*)(src + e0) + t * 4;
        const int4* d4 = (const int4*)(dst + e0) + t * 4;
#pragma unroll
        for (int k = 0; k < 4; ++k) {
            int4 s = s4[k], d = d4[k];
            pk[k*4+0] = ((unsigned)s.x << BSHIFT) | ((unsigned)d.x & (BSZ-1)); bb[k*4+0] = d.x >> BSHIFT;
            pk[k*4+1] = ((unsigned)s.y << BSHIFT) | ((unsigned)d.y & (BSZ-1)); bb[k*4+1] = d.y >> BSHIFT;
            pk[k*4+2] = ((unsigned)s.z << BSHIFT) | ((unsigned)d.z & (BSZ-1)); bb[k*4+2] = d.z >> BSHIFT;
            pk[k*4+3] = ((unsigned)s.w << BSHIFT) | ((unsigned)d.w & (BSZ-1)); bb[k*4+3] = d.w >> BSHIFT;
            atomicAdd(&cnt[bb[k*4+0]], 1u);
            atomicAdd(&cnt[bb[k*4+1]], 1u);
            atomicAdd(&cnt[bb[k*4+2]], 1u);
            atomicAdd(&cnt[bb[k*4+3]], 1u);
        }
    } else {
#pragma unroll
        for (int k = 0; k < 16; ++k) {
            int e = e0 + t * 16 + k;
            if (e < E) {
                int s = src[e], d = dst[e];
                pk[k] = ((unsigned)s << BSHIFT) | ((unsigned)d & (BSZ-1));
                bb[k] = d >> BSHIFT;
                atomicAdd(&cnt[bb[k]], 1u);
            } else bb[k] = -1;
        }
    }
    __syncthreads();
    if (t == 0) {
        unsigned acc = 0;
        for (int b = 0; b < NBK; ++b) { loff[b] = acc; acc += cnt[b]; }
    }
    __syncthreads();
    if (t < NBK && cnt[t] > 0) gbase[t] = atomicAdd(&cursors[t], cnt[t]);
#pragma unroll
    for (int k = 0; k < 16; ++k) {
        if (bb[k] >= 0) {
            unsigned p = loff[bb[k]] + atomicAdd(&run[bb[k]], 1u);
            stage[p] = pk[k];
        }
    }
    __syncthreads();
    for (int b = 0; b < NBK; ++b) {
        unsigned n = cnt[b], lo = loff[b], go = gbase[b];
        unsigned* dp = ebuf + (size_t)b * CAP;
        for (unsigned j = t; j < n; j += BBLK) {
            unsigned pos = go + j;
            if (pos < (unsigned)CAP) dp[pos] = stage[lo + j];
        }
    }
}

__global__ __launch_bounds__(ABLK) void b0_deg_kernel(
        const unsigned* __restrict__ ebuf, const unsigned* __restrict__ cursors,
        unsigned* __restrict__ part) {
    __shared__ unsigned acc[BSZ];               // 32 KB
    int b = blockIdx.x / R1REP, r = blockIdx.x % R1REP;
    for (int j = threadIdx.x; j < BSZ; j += ABLK) acc[j] = 0;
    __syncthreads();
    unsigned c = cursors[b]; if (c > (unsigned)CAP) c = CAP;
    unsigned per = (((c + R1REP - 1) / R1REP) + 15u) & ~15u;
    unsigned i0 = r * per, i1 = i0 + per; if (i1 > c) i1 = c;
    const unsigned* eb = ebuf + (size_t)b * CAP;
    unsigned base = i0 + threadIdx.x * 16;
    for (; base + 16 <= i1; base += ABLK * 16) {
        uv4 p0 = ntload_u4(eb + base);
        uv4 p1 = ntload_u4(eb + base + 4);
        uv4 p2 = ntload_u4(eb + base + 8);
        uv4 p3 = ntload_u4(eb + base + 12);
        atomicAdd(&acc[p0.x & (BSZ-1)], 1u); atomicAdd(&acc[p0.y & (BSZ-1)], 1u);
        atomicAdd(&acc[p0.z & (BSZ-1)], 1u); atomicAdd(&acc[p0.w & (BSZ-1)], 1u);
        atomicAdd(&acc[p1.x & (BSZ-1)], 1u); atomicAdd(&acc[p1.y & (BSZ-1)], 1u);
        atomicAdd(&acc[p1.z & (BSZ-1)], 1u); atomicAdd(&acc[p1.w & (BSZ-1)], 1u);
        atomicAdd(&acc[p2.x & (BSZ-1)], 1u); atomicAdd(&acc[p2.y & (BSZ-1)], 1u);
        atomicAdd(&acc[p2.z & (BSZ-1)], 1u); atomicAdd(&acc[p2.w & (BSZ-1)], 1u);
        atomicAdd(&acc[p3.x & (BSZ-1)], 1u); atomicAdd(&acc[p3.y & (BSZ-1)], 1u);
        atomicAdd(&acc[p3.z & (BSZ-1)], 1u); atomicAdd(&acc[p3.w & (BSZ-1)], 1u);
    }
    for (unsigned i = base; i < i1; ++i) atomicAdd(&acc[eb[i] & (BSZ-1)], 1u);
    __syncthreads();
    unsigned* p = part + (size_t)blockIdx.x * BSZ;
    for (int j = threadIdx.x; j < BSZ; j += ABLK) p[j] = acc[j];
}

__global__ void r0_kernel(const unsigned* __restrict__ part, const float* __restrict__ x,
                          float* __restrict__ dinv, float* __restrict__ xd, int N) {
    int i = blockIdx.x * blockDim.x + threadIdx.x;
    if (i >= N) return;
    int b = i >> BSHIFT, dl = i & (BSZ - 1);
    unsigned deg = 0;
    const unsigned* p = part + (size_t)(b * R1REP) * BSZ + dl;
#pragma unroll 8
    for (int r = 0; r < R1REP; ++r) deg += p[(size_t)r * BSZ];
    float di = rsqrtf((float)deg + 1.0f);
    dinv[i] = di;
    xd[i] = di * x[i];
}

// agg1: i32 fixed-point LDS atomics
__global__ __launch_bounds__(ABLK) void b1_agg1_kernel(
        const unsigned* __restrict__ ebuf, const unsigned* __restrict__ cursors,
        const float* __restrict__ xd, int* __restrict__ part) {
    __shared__ int acc[BSZ];                    // 32 KB
    int b = blockIdx.x / R1REP, r = blockIdx.x % R1REP;
    for (int j = threadIdx.x; j < BSZ; j += ABLK) acc[j] = 0;
    __syncthreads();
    unsigned c = cursors[b]; if (c > (unsigned)CAP) c = CAP;
    unsigned per = (((c + R1REP - 1) / R1REP) + 15u) & ~15u;
    unsigned i0 = r * per, i1 = i0 + per; if (i1 > c) i1 = c;
    const unsigned* eb = ebuf + (size_t)b * CAP;
    unsigned base = i0 + threadIdx.x * 16;
    for (; base + 16 <= i1; base += ABLK * 16) {
        uv4 p0 = ntload_u4(eb + base);
        uv4 p1 = ntload_u4(eb + base + 4);
        uv4 p2 = ntload_u4(eb + base + 8);
        uv4 p3 = ntload_u4(eb + base + 12);
        int q0  = __float2int_rn(xd[p0.x >> BSHIFT] * FXS);
        int q1  = __float2int_rn(xd[p0.y >> BSHIFT] * FXS);
        int q2  = __float2int_rn(xd[p0.z >> BSHIFT] * FXS);
        int q3  = __float2int_rn(xd[p0.w >> BSHIFT] * FXS);
        int q4  = __float2int_rn(xd[p1.x >> BSHIFT] * FXS);
        int q5  = __float2int_rn(xd[p1.y >> BSHIFT] * FXS);
        int q6  = __float2int_rn(xd[p1.z >> BSHIFT] * FXS);
        int q7  = __float2int_rn(xd[p1.w >> BSHIFT] * FXS);
        int q8  = __float2int_rn(xd[p2.x >> BSHIFT] * FXS);
        int q9  = __float2int_rn(xd[p2.y >> BSHIFT] * FXS);
        int q10 = __float2int_rn(xd[p2.z >> BSHIFT] * FXS);
        int q11 = __float2int_rn(xd[p2.w >> BSHIFT] * FXS);
        int q12 = __float2int_rn(xd[p3.x >> BSHIFT] * FXS);
        int q13 = __float2int_rn(xd[p3.y >> BSHIFT] * FXS);
        int q14 = __float2int_rn(xd[p3.z >> BSHIFT] * FXS);
        int q15 = __float2int_rn(xd[p3.w >> BSHIFT] * FXS);
        atomicAdd(&acc[p0.x & (BSZ-1)], q0);  atomicAdd(&acc[p0.y & (BSZ-1)], q1);
        atomicAdd(&acc[p0.z & (BSZ-1)], q2);  atomicAdd(&acc[p0.w & (BSZ-1)], q3);
        atomicAdd(&acc[p1.x & (BSZ-1)], q4);  atomicAdd(&acc[p1.y & (BSZ-1)], q5);
        atomicAdd(&acc[p1.z & (BSZ-1)], q6);  atomicAdd(&acc[p1.w & (BSZ-1)], q7);
        atomicAdd(&acc[p2.x & (BSZ-1)], q8);  atomicAdd(&acc[p2.y & (BSZ-1)], q9);
        atomicAdd(&acc[p2.z & (BSZ-1)], q10); atomicAdd(&acc[p2.w & (BSZ-1)], q11);
        atomicAdd(&acc[p3.x & (BSZ-1)], q12); atomicAdd(&acc[p3.y & (BSZ-1)], q13);
        atomicAdd(&acc[p3.z & (BSZ-1)], q14); atomicAdd(&acc[p3.w & (BSZ-1)], q15);
    }
    for (unsigned i = base; i < i1; ++i) {
        unsigned pk = eb[i];
        atomicAdd(&acc[pk & (BSZ-1)], __float2int_rn(xd[pk >> BSHIFT] * FXS));
    }
    __syncthreads();
    int* p = part + (size_t)blockIdx.x * BSZ;
    for (int j = threadIdx.x; j < BSZ; j += ABLK) p[j] = acc[j];
}

__global__ void r1_kernel(const int* __restrict__ part, const float* __restrict__ x,
                          const float* __restrict__ dinv,
                          const float* __restrict__ W1, const float* __restrict__ b1,
                          const float* __restrict__ W2,
                          float2* __restrict__ ttp, float* __restrict__ os0,
                          float* __restrict__ os1, int N) {
    __shared__ float sW1[32], sb1[32], sW2[64];
    int t = threadIdx.x;
    if (t < 32) { sW1[t] = W1[t]; sb1[t] = b1[t]; }
    if (t < 64) sW2[t] = W2[t];
    __syncthreads();
    int i = blockIdx.x * blockDim.x + t;
    if (i >= N) return;
    int b = i >> BSHIFT, dl = i & (BSZ - 1);
    long long Sq = 0;
    const int* p = part + (size_t)(b * R1REP) * BSZ + dl;
#pragma unroll 8
    for (int r = 0; r < R1REP; ++r) Sq += p[(size_t)r * BSZ];
    float S = (float)Sq * FXI;
    float di = dinv[i];
    float s1v = di * di * x[i] + di * S;
    float a0 = 0.0f, a1 = 0.0f;
#pragma unroll
    for (int j = 0; j < 32; ++j) {
        float h = fmaxf(fmaf(s1v, sW1[j], sb1[j]), 0.0f);
        a0 = fmaf(h, sW2[2 * j], a0);
        a1 = fmaf(h, sW2[2 * j + 1], a1);
    }
    ttp[i] = make_float2(di * a0, di * a1);
    os0[i] = di * di * a0;
    os1[i] = di * di * a1;
}

// agg2: ONE packed u64 LDS atomic per edge (bias 2^31 per addend)
__global__ __launch_bounds__(ABLK) void b2_agg2_kernel(
        const unsigned* __restrict__ ebuf, const unsigned* __restrict__ cursors,
        const float2* __restrict__ ttp, u64* __restrict__ part) {
    __shared__ u64 acc[BSZ];                    // 64 KB
    int b = blockIdx.x / R2REP, r = blockIdx.x % R2REP;
    for (int j = threadIdx.x; j < BSZ; j += ABLK) acc[j] = 0ull;
    __syncthreads();
    unsigned c = cursors[b]; if (c > (unsigned)CAP) c = CAP;
    unsigned per = (((c + R2REP - 1) / R2REP) + 15u) & ~15u;
    unsigned i0 = r * per, i1 = i0 + per; if (i1 > c) i1 = c;
    const unsigned* eb = ebuf + (size_t)b * CAP;
    unsigned base = i0 + threadIdx.x * 16;
    for (; base + 16 <= i1; base += ABLK * 16) {
        uv4 p0 = ntload_u4(eb + base);
        uv4 p1 = ntload_u4(eb + base + 4);
        uv4 p2 = ntload_u4(eb + base + 8);
        uv4 p3 = ntload_u4(eb + base + 12);
        float2 v0  = ttp[p0.x >> BSHIFT], v1  = ttp[p0.y >> BSHIFT];
        float2 v2  = ttp[p0.z >> BSHIFT], v3  = ttp[p0.w >> BSHIFT];
        float2 v4  = ttp[p1.x >> BSHIFT], v5  = ttp[p1.y >> BSHIFT];
        float2 v6  = ttp[p1.z >> BSHIFT], v7  = ttp[p1.w >> BSHIFT];
        float2 v8  = ttp[p2.x >> BSHIFT], v9  = ttp[p2.y >> BSHIFT];
        float2 v10 = ttp[p2.z >> BSHIFT], v11 = ttp[p2.w >> BSHIFT];
        float2 v12 = ttp[p3.x >> BSHIFT], v13 = ttp[p3.y >> BSHIFT];
        float2 v14 = ttp[p3.z >> BSHIFT], v15 = ttp[p3.w >> BSHIFT];
        atomicAdd(&acc[p0.x & (BSZ-1)], pack_fx(v0));
        atomicAdd(&acc[p0.y & (BSZ-1)], pack_fx(v1));
        atomicAdd(&acc[p0.z & (BSZ-1)], pack_fx(v2));
        atomicAdd(&acc[p0.w & (BSZ-1)], pack_fx(v3));
        atomicAdd(&acc[p1.x & (BSZ-1)], pack_fx(v4));
        atomicAdd(&acc[p1.y & (BSZ-1)], pack_fx(v5));
        atomicAdd(&acc[p1.z & (BSZ-1)], pack_fx(v6));
        atomicAdd(&acc[p1.w & (BSZ-1)], pack_fx(v7));
        atomicAdd(&acc[p2.x & (BSZ-1)], pack_fx(v8));
        atomicAdd(&acc[p2.y & (BSZ-1)], pack_fx(v9));
        atomicAdd(&acc[p2.z & (BSZ-1)], pack_fx(v10));
        atomicAdd(&acc[p2.w & (BSZ-1)], pack_fx(v11));
        atomicAdd(&acc[p3.x & (BSZ-1)], pack_fx(v12));
        atomicAdd(&acc[p3.y & (BSZ-1)], pack_fx(v13));
        atomicAdd(&acc[p3.z & (BSZ-1)], pack_fx(v14));
        atomicAdd(&acc[p3.w & (BSZ-1)], pack_fx(v15));
    }
    for (unsigned i = base; i < i1; ++i) {
        unsigned pk = eb[i];
        atomicAdd(&acc[pk & (BSZ-1)], pack_fx(ttp[pk >> BSHIFT]));
    }
    __syncthreads();
    u64* p = part + (size_t)blockIdx.x * BSZ;
    for (int j = threadIdx.x; j < BSZ; j += ABLK) p[j] = acc[j];
}

__global__ void r2_kernel(const u64* __restrict__ part, const float* __restrict__ dinv,
                          const float* __restrict__ os0, const float* __restrict__ os1,
                          const float* __restrict__ b2v, float2* __restrict__ out, int N) {
    int i = blockIdx.x * blockDim.x + threadIdx.x;
    if (i >= N) return;
    int b = i >> BSHIFT, dl = i & (BSZ - 1);
    u64 T = 0ull;
    const u64* p = part + (size_t)(b * R2REP) * BSZ + dl;
#pragma unroll 4
    for (int r = 0; r < R2REP; ++r) T += p[(size_t)r * BSZ];
    float di = dinv[i];
    // recover in-degree: dinv = rsqrt(deg+1) -> deg = round(1/di^2) - 1
    long long cnt = (long long)(int)roundf(1.0f / (di * di)) - 1;
    unsigned low = (unsigned)T;
    unsigned lowbase = (unsigned)((u64)cnt << 31);
    int s0 = (int)(low - lowbase);
    long long Lfull = (cnt << 31) + (long long)s0;
    long long carry = (Lfull - (long long)(u64)low) >> 32;
    unsigned high = (unsigned)(T >> 32);
    int s1 = (int)(high - (unsigned)carry);
    float z0 = di * ((float)s0 * FXI) + os0[i] + b2v[0];
    float z1 = di * ((float)s1 * FXI) + os1[i] + b2v[1];
    float m = fmaxf(z0, z1), mn = fminf(z0, z1);
    float l = m + logf(1.0f + __expf(mn - m));
    out[i] = make_float2(z0 - l, z1 - l);
}

// ---------------- fallback (round-2 verified) ----------------

__global__ void deg_kernel(const int* __restrict__ dst, float* __restrict__ deg, int E) {
    int e = blockIdx.x * blockDim.x + threadIdx.x;
    if (e < E) atomicAdd(&deg[dst[e]], 1.0f);
}

__global__ void dinv_kernel(const float* __restrict__ deg, const float* __restrict__ x,
                            float* __restrict__ dinv, float* __restrict__ s1, int N) {
    int i = blockIdx.x * blockDim.x + threadIdx.x;
    if (i < N) {
        float di = rsqrtf(deg[i] + 1.0f);
        dinv[i] = di;
        s1[i] = di * di * x[i];
    }
}

__global__ void agg1_kernel(const int* __restrict__ src, const int* __restrict__ dst,
                            const float* __restrict__ x, const float* __restrict__ dinv,
                            float* __restrict__ s1, int E) {
    int e = blockIdx.x * blockDim.x + threadIdx.x;
    if (e < E) {
        int s = src[e], d = dst[e];
        atomicAdd(&s1[d], dinv[s] * dinv[d] * x[s]);
    }
}

__global__ void node_mlp_kernel(const float* __restrict__ s1, const float* __restrict__ dinv,
                                const float* __restrict__ W1, const float* __restrict__ b1,
                                const float* __restrict__ W2,
                                float* __restrict__ t0, float* __restrict__ t1,
                                float* __restrict__ o0, float* __restrict__ o1, int N) {
    __shared__ float sW1[32], sb1[32], sW2[64];
    int t = threadIdx.x;
    if (t < 32) { sW1[t] = W1[t]; sb1[t] = b1[t]; }
    if (t < 64) sW2[t] = W2[t];
    __syncthreads();
    int i = blockIdx.x * blockDim.x + t;
    if (i < N) {
        float s = s1[i];
        float a0 = 0.0f, a1 = 0.0f;
#pragma unroll
        for (int j = 0; j < 32; ++j) {
            float h = fmaxf(fmaf(s, sW1[j], sb1[j]), 0.0f);
            a0 = fmaf(h, sW2[2 * j], a0);
            a1 = fmaf(h, sW2[2 * j + 1], a1);
        }
        t0[i] = a0; t1[i] = a1;
        float d2 = dinv[i] * dinv[i];
        o0[i] = d2 * a0; o1[i] = d2 * a1;
    }
}

__global__ void agg2_kernel(const int* __restrict__ src, const int* __restrict__ dst,
                            const float* __restrict__ dinv,
                            const float* __restrict__ t0, const float* __restrict__ t1,
                            float* __restrict__ o0, float* __restrict__ o1, int E) {
    int e = blockIdx.x * blockDim.x + threadIdx.x;
    if (e < E) {
        int s = src[e], d = dst[e];
        float w = dinv[s] * dinv[d];
        atomicAdd(&o0[d], w * t0[s]);
        atomicAdd(&o1[d], w * t1[s]);
    }
}

__global__ void logsoftmax_kernel(const float* __restrict__ o0, const float* __restrict__ o1,
                                  const float* __restrict__ b2, float* __restrict__ out, int N) {
    int i = blockIdx.x * blockDim.x + threadIdx.x;
    if (i < N) {
        float z0 = o0[i] + b2[0];
        float z1 = o1[i] + b2[1];
        float m = fmaxf(z0, z1), mn = fminf(z0, z1);
        float l = m + logf(1.0f + __expf(mn - m));
        ((float2*)out)[i] = make_float2(z0 - l, z1 - l);
    }
}

// ---------------- launch ----------------

extern "C" void kernel_launch(void* const* d_in, const int* in_sizes, int n_in,
                              void* d_out, int out_size, void* d_ws, size_t ws_size,
                              hipStream_t stream) {
    const float* x  = (const float*)d_in[0];
    const int* ei   = (const int*)d_in[1];     // int32 (JAX x64 disabled)
    const float* W1 = (const float*)d_in[2];
    const float* b1 = (const float*)d_in[3];
    const float* W2 = (const float*)d_in[4];
    const float* b2 = (const float*)d_in[5];
    float* out = (float*)d_out;

    const int N = in_sizes[0];
    const int E = in_sizes[1] / 2;
    const int* src = ei;
    const int* dst = ei + E;

    // fast-path ws layout (bytes) -- identical to R4..R8 (proven fit)
    const size_t OFF_CUR  = 0;                                    // 64 u32
    const size_t OFF_EBUF = 256;
    const size_t SZ_EBUF  = (size_t)NBK * CAP * 4;                // 28.1 MB
    const size_t OFF_PART = OFF_EBUF + SZ_EBUF;
    const size_t SZ_PART  = (size_t)NBK * R1REP * BSZ * 4;        // == NBK*R2REP*BSZ*8
    const size_t OFF_NODE = OFF_PART + SZ_PART;
    const size_t SZ_NODE  = (size_t)N * 4;
    const size_t NEED = OFF_NODE + 6 * SZ_NODE + 256;

    bool fast = (ws_size >= NEED) && (N <= NBK * BSZ) && (N < (1 << 17)) && N > 0 &&
                ((size_t)E * BSZ / (size_t)N + 16384 <= (size_t)CAP);

    if (fast) {
        unsigned* cursors = (unsigned*)((char*)d_ws + OFF_CUR);
        unsigned* ebuf    = (unsigned*)((char*)d_ws + OFF_EBUF);
        int*      part    = (int*)((char*)d_ws + OFF_PART);
        float*    dinv    = (float*)((char*)d_ws + OFF_NODE);
        float*    xd      = dinv + N;
        float*    os0     = xd + N;
        float*    os1     = os0 + N;
        float2*   ttp     = (float2*)(os1 + N);                   // 2N floats

        (void)hipMemsetAsync(cursors, 0, 256, stream);

        int ablocks = (E + ACHUNK - 1) / ACHUNK;
        int ng = (N + 255) / 256;

        bucketize_kernel<<<ablocks, BBLK, 0, stream>>>(src, dst, cursors, ebuf, E);
        b0_deg_kernel<<<NBK * R1REP, ABLK, 0, stream>>>(ebuf, cursors, (unsigned*)part);
        r0_kernel<<<ng, 256, 0, stream>>>((unsigned*)part, x, dinv, xd, N);
        b1_agg1_kernel<<<NBK * R1REP, ABLK, 0, stream>>>(ebuf, cursors, xd, part);
        r1_kernel<<<ng, 256, 0, stream>>>(part, x, dinv, W1, b1, W2, ttp, os0, os1, N);
        b2_agg2_kernel<<<NBK * R2REP, ABLK, 0, stream>>>(ebuf, cursors, ttp, (u64*)part);
        r2_kernel<<<ng, 256, 0, stream>>>((const u64*)part, dinv, os0, os1, b2, (float2*)out, N);
    } else {
        float* deg  = (float*)d_ws;
        float* dinv = deg + N;
        float* s1   = dinv + N;
        float* t0   = s1 + N;
        float* t1   = t0 + N;
        float* o0   = t1 + N;
        float* o1   = o0 + N;

        (void)hipMemsetAsync(deg, 0, (size_t)N * sizeof(float), stream);
        int eg = (E + 255) / 256, ng = (N + 255) / 256;
        deg_kernel<<<eg, 256, 0, stream>>>(dst, deg, E);
        dinv_kernel<<<ng, 256, 0, stream>>>(deg, x, dinv, s1, N);
        agg1_kernel<<<eg, 256, 0, stream>>>(src, dst, x, dinv, s1, E);
        node_mlp_kernel<<<ng, 256, 0, stream>>>(s1, dinv, W1, b1, W2, t0, t1, o0, o1, N);
        agg2_kernel<<<eg, 256, 0, stream>>>(src, dst, dinv, t0, t1, o0, o1, E);
        logsoftmax_kernel<<<ng, 256, 0, stream>>>(o0, o1, b2, out, N);
    }
}

// Round 10
// 213.711 us; speedup vs baseline: 1.0014x; 1.0014x over previous
//
#include <hip/hip_runtime.h>
#include <math.h>

// GCN 2-layer, MI355X. Round 10: R9 showed u64 atomic == 2x i32 bank-ops
// (zero gain) -> LDS pipe charges per 4B bank-op. New theory: grids of 260
// (b2) / 520 (b0,b1) blocks on 256 CUs leave the busiest CU with 2x / 1.5x
// work (LDS-pipe timeshared) -> straggler-bound; occ 15% = busy-then-idle.
// Fix: replicas 19 (13*19=247 <= 256 blocks, 1/CU), bucketize persistent
// grid=256 with balanced 25000-edge ranges. ws layout unchanged.

#define NBK     13
#define BSHIFT  13
#define BSZ     8192            // nodes per bucket
#define CAP     540672          // per-bucket edge capacity = 524288 + 16384 (23 sigma)
#define R1REP   19              // replicas/bucket for deg & agg1 (grid 247)
#define R2REP   19              // replicas/bucket for agg2 (grid 247)
#define ABLK    512             // threads for agg kernels
#define BBLK    512             // threads for bucketize
#define ACHUNK  8192            // edges per bucketize stage chunk (16/thread)
#define BGRID   256             // bucketize persistent grid

#define FXS     1048576.0f          // 2^20
#define FXI     9.5367431640625e-7f // 2^-20

typedef unsigned uv4 __attribute__((ext_vector_type(4)));
typedef unsigned long long u64;

__device__ __forceinline__ uv4 ntload_u4(const unsigned* p) {
    return __builtin_nontemporal_load((const uv4*)p);
}

__device__ __forceinline__ u64 pack_fx(float2 v) {
    int q0 = __float2int_rn(v.x * FXS);
    int q1 = __float2int_rn(v.y * FXS);
    return ((u64)(unsigned)q1 << 32) + (u64)(unsigned)q0 + 0x80000000ull;
}

// ---------------- fast path kernels ----------------

// Persistent balanced bucketize: each block owns a contiguous ~E/256 range,
// loops over 8192-edge stage chunks (R5-verified inner structure).
__global__ __launch_bounds__(BBLK) void bucketize_kernel(
        const int* __restrict__ src, const int* __restrict__ dst,
        unsigned* __restrict__ cursors, unsigned* __restrict__ ebuf, int E) {
    __shared__ unsigned stage[ACHUNK];          // 32 KB
    __shared__ unsigned cnt[NBK], gbase[NBK], loff[NBK], run[NBK];
    int t = threadIdx.x;
    int per = (E + (int)gridDim.x - 1) / (int)gridDim.x;
    per = (per + 3) & ~3;                       // keep 16B alignment of range starts
    int rb = blockIdx.x * per;
    int re = rb + per; if (re > E) re = E;
    for (int c0 = rb; c0 < re; c0 += ACHUNK) {
        int clen = re - c0; if (clen > ACHUNK) clen = ACHUNK;
        if (t < NBK) { cnt[t] = 0; run[t] = 0; }
        __syncthreads();
        unsigned pk[16];
        int bb[16];
        if (clen == ACHUNK) {
            const int4* s4 = (const int4*)(src + c0) + t * 4;
            const int4* d4 = (const int4*)(dst + c0) + t * 4;
#pragma unroll
            for (int k = 0; k < 4; ++k) {
                int4 s = s4[k], d = d4[k];
                pk[k*4+0] = ((unsigned)s.x << BSHIFT) | ((unsigned)d.x & (BSZ-1)); bb[k*4+0] = d.x >> BSHIFT;
                pk[k*4+1] = ((unsigned)s.y << BSHIFT) | ((unsigned)d.y & (BSZ-1)); bb[k*4+1] = d.y >> BSHIFT;
                pk[k*4+2] = ((unsigned)s.z << BSHIFT) | ((unsigned)d.z & (BSZ-1)); bb[k*4+2] = d.z >> BSHIFT;
                pk[k*4+3] = ((unsigned)s.w << BSHIFT) | ((unsigned)d.w & (BSZ-1)); bb[k*4+3] = d.w >> BSHIFT;
                atomicAdd(&cnt[bb[k*4+0]], 1u);
                atomicAdd(&cnt[bb[k*4+1]], 1u);
                atomicAdd(&cnt[bb[k*4+2]], 1u);
                atomicAdd(&cnt[bb[k*4+3]], 1u);
            }
        } else {
#pragma unroll
            for (int k = 0; k < 16; ++k) {
                int e = c0 + t * 16 + k;
                if (e < c0 + clen) {
                    int s = src[e], d = dst[e];
                    pk[k] = ((unsigned)s << BSHIFT) | ((unsigned)d & (BSZ-1));
                    bb[k] = d >> BSHIFT;
                    atomicAdd(&cnt[bb[k]], 1u);
                } else bb[k] = -1;
            }
        }
        __syncthreads();
        if (t == 0) {
            unsigned acc = 0;
            for (int b = 0; b < NBK; ++b) { loff[b] = acc; acc += cnt[b]; }
        }
        __syncthreads();
        if (t < NBK && cnt[t] > 0) gbase[t] = atomicAdd(&cursors[t], cnt[t]);
#pragma unroll
        for (int k = 0; k < 16; ++k) {
            if (bb[k] >= 0) {
                unsigned p = loff[bb[k]] + atomicAdd(&run[bb[k]], 1u);
                stage[p] = pk[k];
            }
        }
        __syncthreads();
        for (int b = 0; b < NBK; ++b) {
            unsigned n = cnt[b], lo = loff[b], go = gbase[b];
            unsigned* dp = ebuf + (size_t)b * CAP;
            for (unsigned j = t; j < n; j += BBLK) {
                unsigned pos = go + j;
                if (pos < (unsigned)CAP) dp[pos] = stage[lo + j];
            }
        }
        __syncthreads();
    }
}

__global__ __launch_bounds__(ABLK) void b0_deg_kernel(
        const unsigned* __restrict__ ebuf, const unsigned* __restrict__ cursors,
        unsigned* __restrict__ part) {
    __shared__ unsigned acc[BSZ];               // 32 KB
    int b = blockIdx.x / R1REP, r = blockIdx.x % R1REP;
    for (int j = threadIdx.x; j < BSZ; j += ABLK) acc[j] = 0;
    __syncthreads();
    unsigned c = cursors[b]; if (c > (unsigned)CAP) c = CAP;
    unsigned per = (((c + R1REP - 1) / R1REP) + 15u) & ~15u;
    unsigned i0 = r * per, i1 = i0 + per; if (i1 > c) i1 = c;
    const unsigned* eb = ebuf + (size_t)b * CAP;
    unsigned base = i0 + threadIdx.x * 16;
    for (; base + 16 <= i1; base += ABLK * 16) {
        uv4 p0 = ntload_u4(eb + base);
        uv4 p1 = ntload_u4(eb + base + 4);
        uv4 p2 = ntload_u4(eb + base + 8);
        uv4 p3 = ntload_u4(eb + base + 12);
        atomicAdd(&acc[p0.x & (BSZ-1)], 1u); atomicAdd(&acc[p0.y & (BSZ-1)], 1u);
        atomicAdd(&acc[p0.z & (BSZ-1)], 1u); atomicAdd(&acc[p0.w & (BSZ-1)], 1u);
        atomicAdd(&acc[p1.x & (BSZ-1)], 1u); atomicAdd(&acc[p1.y & (BSZ-1)], 1u);
        atomicAdd(&acc[p1.z & (BSZ-1)], 1u); atomicAdd(&acc[p1.w & (BSZ-1)], 1u);
        atomicAdd(&acc[p2.x & (BSZ-1)], 1u); atomicAdd(&acc[p2.y & (BSZ-1)], 1u);
        atomicAdd(&acc[p2.z & (BSZ-1)], 1u); atomicAdd(&acc[p2.w & (BSZ-1)], 1u);
        atomicAdd(&acc[p3.x & (BSZ-1)], 1u); atomicAdd(&acc[p3.y & (BSZ-1)], 1u);
        atomicAdd(&acc[p3.z & (BSZ-1)], 1u); atomicAdd(&acc[p3.w & (BSZ-1)], 1u);
    }
    for (unsigned i = base; i < i1; ++i) atomicAdd(&acc[eb[i] & (BSZ-1)], 1u);
    __syncthreads();
    unsigned* p = part + (size_t)blockIdx.x * BSZ;
    for (int j = threadIdx.x; j < BSZ; j += ABLK) p[j] = acc[j];
}

__global__ void r0_kernel(const unsigned* __restrict__ part, const float* __restrict__ x,
                          float* __restrict__ dinv, float* __restrict__ xd, int N) {
    int i = blockIdx.x * blockDim.x + threadIdx.x;
    if (i >= N) return;
    int b = i >> BSHIFT, dl = i & (BSZ - 1);
    unsigned deg = 0;
    const unsigned* p = part + (size_t)(b * R1REP) * BSZ + dl;
#pragma unroll
    for (int r = 0; r < R1REP; ++r) deg += p[(size_t)r * BSZ];
    float di = rsqrtf((float)deg + 1.0f);
    dinv[i] = di;
    xd[i] = di * x[i];
}

// agg1: i32 fixed-point LDS atomics
__global__ __launch_bounds__(ABLK) void b1_agg1_kernel(
        const unsigned* __restrict__ ebuf, const unsigned* __restrict__ cursors,
        const float* __restrict__ xd, int* __restrict__ part) {
    __shared__ int acc[BSZ];                    // 32 KB
    int b = blockIdx.x / R1REP, r = blockIdx.x % R1REP;
    for (int j = threadIdx.x; j < BSZ; j += ABLK) acc[j] = 0;
    __syncthreads();
    unsigned c = cursors[b]; if (c > (unsigned)CAP) c = CAP;
    unsigned per = (((c + R1REP - 1) / R1REP) + 15u) & ~15u;
    unsigned i0 = r * per, i1 = i0 + per; if (i1 > c) i1 = c;
    const unsigned* eb = ebuf + (size_t)b * CAP;
    unsigned base = i0 + threadIdx.x * 16;
    for (; base + 16 <= i1; base += ABLK * 16) {
        uv4 p0 = ntload_u4(eb + base);
        uv4 p1 = ntload_u4(eb + base + 4);
        uv4 p2 = ntload_u4(eb + base + 8);
        uv4 p3 = ntload_u4(eb + base + 12);
        int q0  = __float2int_rn(xd[p0.x >> BSHIFT] * FXS);
        int q1  = __float2int_rn(xd[p0.y >> BSHIFT] * FXS);
        int q2  = __float2int_rn(xd[p0.z >> BSHIFT] * FXS);
        int q3  = __float2int_rn(xd[p0.w >> BSHIFT] * FXS);
        int q4  = __float2int_rn(xd[p1.x >> BSHIFT] * FXS);
        int q5  = __float2int_rn(xd[p1.y >> BSHIFT] * FXS);
        int q6  = __float2int_rn(xd[p1.z >> BSHIFT] * FXS);
        int q7  = __float2int_rn(xd[p1.w >> BSHIFT] * FXS);
        int q8  = __float2int_rn(xd[p2.x >> BSHIFT] * FXS);
        int q9  = __float2int_rn(xd[p2.y >> BSHIFT] * FXS);
        int q10 = __float2int_rn(xd[p2.z >> BSHIFT] * FXS);
        int q11 = __float2int_rn(xd[p2.w >> BSHIFT] * FXS);
        int q12 = __float2int_rn(xd[p3.x >> BSHIFT] * FXS);
        int q13 = __float2int_rn(xd[p3.y >> BSHIFT] * FXS);
        int q14 = __float2int_rn(xd[p3.z >> BSHIFT] * FXS);
        int q15 = __float2int_rn(xd[p3.w >> BSHIFT] * FXS);
        atomicAdd(&acc[p0.x & (BSZ-1)], q0);  atomicAdd(&acc[p0.y & (BSZ-1)], q1);
        atomicAdd(&acc[p0.z & (BSZ-1)], q2);  atomicAdd(&acc[p0.w & (BSZ-1)], q3);
        atomicAdd(&acc[p1.x & (BSZ-1)], q4);  atomicAdd(&acc[p1.y & (BSZ-1)], q5);
        atomicAdd(&acc[p1.z & (BSZ-1)], q6);  atomicAdd(&acc[p1.w & (BSZ-1)], q7);
        atomicAdd(&acc[p2.x & (BSZ-1)], q8);  atomicAdd(&acc[p2.y & (BSZ-1)], q9);
        atomicAdd(&acc[p2.z & (BSZ-1)], q10); atomicAdd(&acc[p2.w & (BSZ-1)], q11);
        atomicAdd(&acc[p3.x & (BSZ-1)], q12); atomicAdd(&acc[p3.y & (BSZ-1)], q13);
        atomicAdd(&acc[p3.z & (BSZ-1)], q14); atomicAdd(&acc[p3.w & (BSZ-1)], q15);
    }
    for (unsigned i = base; i < i1; ++i) {
        unsigned pk = eb[i];
        atomicAdd(&acc[pk & (BSZ-1)], __float2int_rn(xd[pk >> BSHIFT] * FXS));
    }
    __syncthreads();
    int* p = part + (size_t)blockIdx.x * BSZ;
    for (int j = threadIdx.x; j < BSZ; j += ABLK) p[j] = acc[j];
}

__global__ void r1_kernel(const int* __restrict__ part, const float* __restrict__ x,
                          const float* __restrict__ dinv,
                          const float* __restrict__ W1, const float* __restrict__ b1,
                          const float* __restrict__ W2,
                          float2* __restrict__ ttp, float* __restrict__ os0,
                          float* __restrict__ os1, int N) {
    __shared__ float sW1[32], sb1[32], sW2[64];
    int t = threadIdx.x;
    if (t < 32) { sW1[t] = W1[t]; sb1[t] = b1[t]; }
    if (t < 64) sW2[t] = W2[t];
    __syncthreads();
    int i = blockIdx.x * blockDim.x + t;
    if (i >= N) return;
    int b = i >> BSHIFT, dl = i & (BSZ - 1);
    long long Sq = 0;
    const int* p = part + (size_t)(b * R1REP) * BSZ + dl;
#pragma unroll
    for (int r = 0; r < R1REP; ++r) Sq += p[(size_t)r * BSZ];
    float S = (float)Sq * FXI;
    float di = dinv[i];
    float s1v = di * di * x[i] + di * S;
    float a0 = 0.0f, a1 = 0.0f;
#pragma unroll
    for (int j = 0; j < 32; ++j) {
        float h = fmaxf(fmaf(s1v, sW1[j], sb1[j]), 0.0f);
        a0 = fmaf(h, sW2[2 * j], a0);
        a1 = fmaf(h, sW2[2 * j + 1], a1);
    }
    ttp[i] = make_float2(di * a0, di * a1);
    os0[i] = di * di * a0;
    os1[i] = di * di * a1;
}

// agg2: one packed u64 LDS atomic per edge (bias 2^31 per addend)
__global__ __launch_bounds__(ABLK) void b2_agg2_kernel(
        const unsigned* __restrict__ ebuf, const unsigned* __restrict__ cursors,
        const float2* __restrict__ ttp, u64* __restrict__ part) {
    __shared__ u64 acc[BSZ];                    // 64 KB
    int b = blockIdx.x / R2REP, r = blockIdx.x % R2REP;
    for (int j = threadIdx.x; j < BSZ; j += ABLK) acc[j] = 0ull;
    __syncthreads();
    unsigned c = cursors[b]; if (c > (unsigned)CAP) c = CAP;
    unsigned per = (((c + R2REP - 1) / R2REP) + 15u) & ~15u;
    unsigned i0 = r * per, i1 = i0 + per; if (i1 > c) i1 = c;
    const unsigned* eb = ebuf + (size_t)b * CAP;
    unsigned base = i0 + threadIdx.x * 16;
    for (; base + 16 <= i1; base += ABLK * 16) {
        uv4 p0 = ntload_u4(eb + base);
        uv4 p1 = ntload_u4(eb + base + 4);
        uv4 p2 = ntload_u4(eb + base + 8);
        uv4 p3 = ntload_u4(eb + base + 12);
        float2 v0  = ttp[p0.x >> BSHIFT], v1  = ttp[p0.y >> BSHIFT];
        float2 v2  = ttp[p0.z >> BSHIFT], v3  = ttp[p0.w >> BSHIFT];
        float2 v4  = ttp[p1.x >> BSHIFT], v5  = ttp[p1.y >> BSHIFT];
        float2 v6  = ttp[p1.z >> BSHIFT], v7  = ttp[p1.w >> BSHIFT];
        float2 v8  = ttp[p2.x >> BSHIFT], v9  = ttp[p2.y >> BSHIFT];
        float2 v10 = ttp[p2.z >> BSHIFT], v11 = ttp[p2.w >> BSHIFT];
        float2 v12 = ttp[p3.x >> BSHIFT], v13 = ttp[p3.y >> BSHIFT];
        float2 v14 = ttp[p3.z >> BSHIFT], v15 = ttp[p3.w >> BSHIFT];
        atomicAdd(&acc[p0.x & (BSZ-1)], pack_fx(v0));
        atomicAdd(&acc[p0.y & (BSZ-1)], pack_fx(v1));
        atomicAdd(&acc[p0.z & (BSZ-1)], pack_fx(v2));
        atomicAdd(&acc[p0.w & (BSZ-1)], pack_fx(v3));
        atomicAdd(&acc[p1.x & (BSZ-1)], pack_fx(v4));
        atomicAdd(&acc[p1.y & (BSZ-1)], pack_fx(v5));
        atomicAdd(&acc[p1.z & (BSZ-1)], pack_fx(v6));
        atomicAdd(&acc[p1.w & (BSZ-1)], pack_fx(v7));
        atomicAdd(&acc[p2.x & (BSZ-1)], pack_fx(v8));
        atomicAdd(&acc[p2.y & (BSZ-1)], pack_fx(v9));
        atomicAdd(&acc[p2.z & (BSZ-1)], pack_fx(v10));
        atomicAdd(&acc[p2.w & (BSZ-1)], pack_fx(v11));
        atomicAdd(&acc[p3.x & (BSZ-1)], pack_fx(v12));
        atomicAdd(&acc[p3.y & (BSZ-1)], pack_fx(v13));
        atomicAdd(&acc[p3.z & (BSZ-1)], pack_fx(v14));
        atomicAdd(&acc[p3.w & (BSZ-1)], pack_fx(v15));
    }
    for (unsigned i = base; i < i1; ++i) {
        unsigned pk = eb[i];
        atomicAdd(&acc[pk & (BSZ-1)], pack_fx(ttp[pk >> BSHIFT]));
    }
    __syncthreads();
    u64* p = part + (size_t)blockIdx.x * BSZ;
    for (int j = threadIdx.x; j < BSZ; j += ABLK) p[j] = acc[j];
}

__global__ void r2_kernel(const u64* __restrict__ part, const float* __restrict__ dinv,
                          const float* __restrict__ os0, const float* __restrict__ os1,
                          const float* __restrict__ b2v, float2* __restrict__ out, int N) {
    int i = blockIdx.x * blockDim.x + threadIdx.x;
    if (i >= N) return;
    int b = i >> BSHIFT, dl = i & (BSZ - 1);
    u64 T = 0ull;
    const u64* p = part + (size_t)(b * R2REP) * BSZ + dl;
#pragma unroll
    for (int r = 0; r < R2REP; ++r) T += p[(size_t)r * BSZ];
    float di = dinv[i];
    // recover in-degree: dinv = rsqrt(deg+1) -> deg = round(1/di^2) - 1
    long long cnt = (long long)(int)roundf(1.0f / (di * di)) - 1;
    unsigned low = (unsigned)T;
    unsigned lowbase = (unsigned)((u64)cnt << 31);
    int s0 = (int)(low - lowbase);
    long long Lfull = (cnt << 31) + (long long)s0;
    long long carry = (Lfull - (long long)(u64)low) >> 32;
    unsigned high = (unsigned)(T >> 32);
    int s1 = (int)(high - (unsigned)carry);
    float z0 = di * ((float)s0 * FXI) + os0[i] + b2v[0];
    float z1 = di * ((float)s1 * FXI) + os1[i] + b2v[1];
    float m = fmaxf(z0, z1), mn = fminf(z0, z1);
    float l = m + logf(1.0f + __expf(mn - m));
    out[i] = make_float2(z0 - l, z1 - l);
}

// ---------------- fallback (round-2 verified) ----------------

__global__ void deg_kernel(const int* __restrict__ dst, float* __restrict__ deg, int E) {
    int e = blockIdx.x * blockDim.x + threadIdx.x;
    if (e < E) atomicAdd(&deg[dst[e]], 1.0f);
}

__global__ void dinv_kernel(const float* __restrict__ deg, const float* __restrict__ x,
                            float* __restrict__ dinv, float* __restrict__ s1, int N) {
    int i = blockIdx.x * blockDim.x + threadIdx.x;
    if (i < N) {
        float di = rsqrtf(deg[i] + 1.0f);
        dinv[i] = di;
        s1[i] = di * di * x[i];
    }
}

__global__ void agg1_kernel(const int* __restrict__ src, const int* __restrict__ dst,
                            const float* __restrict__ x, const float* __restrict__ dinv,
                            float* __restrict__ s1, int E) {
    int e = blockIdx.x * blockDim.x + threadIdx.x;
    if (e < E) {
        int s = src[e], d = dst[e];
        atomicAdd(&s1[d], dinv[s] * dinv[d] * x[s]);
    }
}

__global__ void node_mlp_kernel(const float* __restrict__ s1, const float* __restrict__ dinv,
                                const float* __restrict__ W1, const float* __restrict__ b1,
                                const float* __restrict__ W2,
                                float* __restrict__ t0, float* __restrict__ t1,
                                float* __restrict__ o0, float* __restrict__ o1, int N) {
    __shared__ float sW1[32], sb1[32], sW2[64];
    int t = threadIdx.x;
    if (t < 32) { sW1[t] = W1[t]; sb1[t] = b1[t]; }
    if (t < 64) sW2[t] = W2[t];
    __syncthreads();
    int i = blockIdx.x * blockDim.x + t;
    if (i < N) {
        float s = s1[i];
        float a0 = 0.0f, a1 = 0.0f;
#pragma unroll
        for (int j = 0; j < 32; ++j) {
            float h = fmaxf(fmaf(s, sW1[j], sb1[j]), 0.0f);
            a0 = fmaf(h, sW2[2 * j], a0);
            a1 = fmaf(h, sW2[2 * j + 1], a1);
        }
        t0[i] = a0; t1[i] = a1;
        float d2 = dinv[i] * dinv[i];
        o0[i] = d2 * a0; o1[i] = d2 * a1;
    }
}

__global__ void agg2_kernel(const int* __restrict__ src, const int* __restrict__ dst,
                            const float* __restrict__ dinv,
                            const float* __restrict__ t0, const float* __restrict__ t1,
                            float* __restrict__ o0, float* __restrict__ o1, int E) {
    int e = blockIdx.x * blockDim.x + threadIdx.x;
    if (e < E) {
        int s = src[e], d = dst[e];
        float w = dinv[s] * dinv[d];
        atomicAdd(&o0[d], w * t0[s]);
        atomicAdd(&o1[d], w * t1[s]);
    }
}

__global__ void logsoftmax_kernel(const float* __restrict__ o0, const float* __restrict__ o1,
                                  const float* __restrict__ b2, float* __restrict__ out, int N) {
    int i = blockIdx.x * blockDim.x + threadIdx.x;
    if (i < N) {
        float z0 = o0[i] + b2[0];
        float z1 = o1[i] + b2[1];
        float m = fmaxf(z0, z1), mn = fminf(z0, z1);
        float l = m + logf(1.0f + __expf(mn - m));
        ((float2*)out)[i] = make_float2(z0 - l, z1 - l);
    }
}

// ---------------- launch ----------------

extern "C" void kernel_launch(void* const* d_in, const int* in_sizes, int n_in,
                              void* d_out, int out_size, void* d_ws, size_t ws_size,
                              hipStream_t stream) {
    const float* x  = (const float*)d_in[0];
    const int* ei   = (const int*)d_in[1];     // int32 (JAX x64 disabled)
    const float* W1 = (const float*)d_in[2];
    const float* b1 = (const float*)d_in[3];
    const float* W2 = (const float*)d_in[4];
    const float* b2 = (const float*)d_in[5];
    float* out = (float*)d_out;

    const int N = in_sizes[0];
    const int E = in_sizes[1] / 2;
    const int* src = ei;
    const int* dst = ei + E;

    // fast-path ws layout (bytes) -- identical to R4..R9 (proven fit).
    // SZ_PART kept at the old 40-replica size; usage is 247*BSZ*8 = 16.2MB < 17.0MB.
    const size_t OFF_CUR  = 0;                                    // 64 u32
    const size_t OFF_EBUF = 256;
    const size_t SZ_EBUF  = (size_t)NBK * CAP * 4;                // 28.1 MB
    const size_t OFF_PART = OFF_EBUF + SZ_EBUF;
    const size_t SZ_PART  = (size_t)NBK * 40 * BSZ * 4;           // 17.0 MB (legacy size)
    const size_t OFF_NODE = OFF_PART + SZ_PART;
    const size_t SZ_NODE  = (size_t)N * 4;
    const size_t NEED = OFF_NODE + 6 * SZ_NODE + 256;

    bool fast = (ws_size >= NEED) && (N <= NBK * BSZ) && (N < (1 << 17)) && N > 0 &&
                ((size_t)E * BSZ / (size_t)N + 16384 <= (size_t)CAP);

    if (fast) {
        unsigned* cursors = (unsigned*)((char*)d_ws + OFF_CUR);
        unsigned* ebuf    = (unsigned*)((char*)d_ws + OFF_EBUF);
        int*      part    = (int*)((char*)d_ws + OFF_PART);
        float*    dinv    = (float*)((char*)d_ws + OFF_NODE);
        float*    xd      = dinv + N;
        float*    os0     = xd + N;
        float*    os1     = os0 + N;
        float2*   ttp     = (float2*)(os1 + N);                   // 2N floats

        (void)hipMemsetAsync(cursors, 0, 256, stream);

        int ng = (N + 255) / 256;

        bucketize_kernel<<<BGRID, BBLK, 0, stream>>>(src, dst, cursors, ebuf, E);
        b0_deg_kernel<<<NBK * R1REP, ABLK, 0, stream>>>(ebuf, cursors, (unsigned*)part);
        r0_kernel<<<ng, 256, 0, stream>>>((unsigned*)part, x, dinv, xd, N);
        b1_agg1_kernel<<<NBK * R1REP, ABLK, 0, stream>>>(ebuf, cursors, xd, part);
        r1_kernel<<<ng, 256, 0, stream>>>(part, x, dinv, W1, b1, W2, ttp, os0, os1, N);
        b2_agg2_kernel<<<NBK * R2REP, ABLK, 0, stream>>>(ebuf, cursors, ttp, (u64*)part);
        r2_kernel<<<ng, 256, 0, stream>>>((const u64*)part, dinv, os0, os1, b2, (float2*)out, N);
    } else {
        float* deg  = (float*)d_ws;
        float* dinv = deg + N;
        float* s1   = dinv + N;
        float* t0   = s1 + N;
        float* t1   = t0 + N;
        float* o0   = t1 + N;
        float* o1   = o0 + N;

        (void)hipMemsetAsync(deg, 0, (size_t)N * sizeof(float), stream);
        int eg = (E + 255) / 256, ng = (N + 255) / 256;
        deg_kernel<<<eg, 256, 0, stream>>>(dst, deg, E);
        dinv_kernel<<<ng, 256, 0, stream>>>(deg, x, dinv, s1, N);
        agg1_kernel<<<eg, 256, 0, stream>>>(src, dst, x, dinv, s1, E);
        node_mlp_kernel<<<ng, 256, 0, stream>>>(s1, dinv, W1, b1, W2, t0, t1, o0, o1, N);
        agg2_kernel<<<eg, 256, 0, stream>>>(src, dst, dinv, t0, t1, o0, o1, E);
        logsoftmax_kernel<<<ng, 256, 0, stream>>>(o0, o1, b2, out, N);
    }
}

// Round 11
// 206.283 us; speedup vs baseline: 1.0374x; 1.0360x over previous
//
#include <hip/hip_runtime.h>
#include <math.h>

// GCN 2-layer, MI355X. Round 11: R10 counters gave the cost model
// (LDS atomic ~1.3 cyc/edge/CU, gather ~1 cyc) and showed bucketize top at
// 4.2 cyc/edge (2 contended LDS atomics + LDS stage write+read). This round:
// bucketize with ONE LDS atomic/edge, ranks in registers, direct global
// scatter (dense ranks -> contiguous per-bucket window per chunk, L2
// write-combined), no 32KB stage (more resident waves). Readers and ws
// layout byte-identical to R10. ws_size measured 268 MB (fill counter).

#define NBK     13
#define BSHIFT  13
#define BSZ     8192            // nodes per bucket
#define CAP     540672          // per-bucket edge capacity = 524288 + 16384 (23 sigma)
#define R1REP   19              // replicas/bucket for deg & agg1 (grid 247)
#define R2REP   19              // replicas/bucket for agg2 (grid 247)
#define ABLK    512             // threads for agg kernels
#define BBLK    512             // threads for bucketize
#define ACHUNK  8192            // edges per bucketize chunk (16/thread)
#define BGRID   256             // bucketize persistent grid

#define FXS     1048576.0f          // 2^20
#define FXI     9.5367431640625e-7f // 2^-20

typedef unsigned uv4 __attribute__((ext_vector_type(4)));
typedef unsigned long long u64;

__device__ __forceinline__ uv4 ntload_u4(const unsigned* p) {
    return __builtin_nontemporal_load((const uv4*)p);
}

__device__ __forceinline__ u64 pack_fx(float2 v) {
    int q0 = __float2int_rn(v.x * FXS);
    int q1 = __float2int_rn(v.y * FXS);
    return ((u64)(unsigned)q1 << 32) + (u64)(unsigned)q0 + 0x80000000ull;
}

// ---------------- fast path kernels ----------------

// Bucketize: per chunk, rank edges with ONE LDS atomic each, reserve global
// cursor space per bucket, scatter directly to ebuf (dense contiguous window
// per bucket per chunk -> L2 write-combining). No LDS stage.
__global__ __launch_bounds__(BBLK) void bucketize_kernel(
        const int* __restrict__ src, const int* __restrict__ dst,
        unsigned* __restrict__ cursors, unsigned* __restrict__ ebuf, int E) {
    __shared__ unsigned run[NBK], gbase[NBK];
    int t = threadIdx.x;
    int per = (E + (int)gridDim.x - 1) / (int)gridDim.x;
    per = (per + 3) & ~3;                       // 16B-aligned range starts
    int rb = blockIdx.x * per;
    int re = rb + per; if (re > E) re = E;
    for (int c0 = rb; c0 < re; c0 += ACHUNK) {
        int clen = re - c0; if (clen > ACHUNK) clen = ACHUNK;
        if (t < NBK) run[t] = 0;
        __syncthreads();
        unsigned pk[16], rk[16];
        int bb[16];
        if (clen == ACHUNK) {
            const int4* s4 = (const int4*)(src + c0) + t * 4;
            const int4* d4 = (const int4*)(dst + c0) + t * 4;
#pragma unroll
            for (int k = 0; k < 4; ++k) {
                int4 s = s4[k], d = d4[k];
                pk[k*4+0] = ((unsigned)s.x << BSHIFT) | ((unsigned)d.x & (BSZ-1)); bb[k*4+0] = d.x >> BSHIFT;
                pk[k*4+1] = ((unsigned)s.y << BSHIFT) | ((unsigned)d.y & (BSZ-1)); bb[k*4+1] = d.y >> BSHIFT;
                pk[k*4+2] = ((unsigned)s.z << BSHIFT) | ((unsigned)d.z & (BSZ-1)); bb[k*4+2] = d.z >> BSHIFT;
                pk[k*4+3] = ((unsigned)s.w << BSHIFT) | ((unsigned)d.w & (BSZ-1)); bb[k*4+3] = d.w >> BSHIFT;
            }
#pragma unroll
            for (int k = 0; k < 16; ++k)
                rk[k] = atomicAdd(&run[bb[k]], 1u);
        } else {
#pragma unroll
            for (int k = 0; k < 16; ++k) {
                int e = c0 + t * 16 + k;
                if (e < c0 + clen) {
                    int s = src[e], d = dst[e];
                    pk[k] = ((unsigned)s << BSHIFT) | ((unsigned)d & (BSZ-1));
                    bb[k] = d >> BSHIFT;
                    rk[k] = atomicAdd(&run[bb[k]], 1u);
                } else bb[k] = -1;
            }
        }
        __syncthreads();
        if (t < NBK) {
            unsigned c = run[t];
            gbase[t] = c ? atomicAdd(&cursors[t], c) : 0u;
        }
        __syncthreads();
#pragma unroll
        for (int k = 0; k < 16; ++k) {
            if (bb[k] >= 0) {
                unsigned pos = gbase[bb[k]] + rk[k];
                if (pos < (unsigned)CAP)
                    ebuf[(size_t)bb[k] * CAP + pos] = pk[k];
            }
        }
        __syncthreads();
    }
}

__global__ __launch_bounds__(ABLK) void b0_deg_kernel(
        const unsigned* __restrict__ ebuf, const unsigned* __restrict__ cursors,
        unsigned* __restrict__ part) {
    __shared__ unsigned acc[BSZ];               // 32 KB
    int b = blockIdx.x / R1REP, r = blockIdx.x % R1REP;
    for (int j = threadIdx.x; j < BSZ; j += ABLK) acc[j] = 0;
    __syncthreads();
    unsigned c = cursors[b]; if (c > (unsigned)CAP) c = CAP;
    unsigned per = (((c + R1REP - 1) / R1REP) + 15u) & ~15u;
    unsigned i0 = r * per, i1 = i0 + per; if (i1 > c) i1 = c;
    const unsigned* eb = ebuf + (size_t)b * CAP;
    unsigned base = i0 + threadIdx.x * 16;
    for (; base + 16 <= i1; base += ABLK * 16) {
        uv4 p0 = ntload_u4(eb + base);
        uv4 p1 = ntload_u4(eb + base + 4);
        uv4 p2 = ntload_u4(eb + base + 8);
        uv4 p3 = ntload_u4(eb + base + 12);
        atomicAdd(&acc[p0.x & (BSZ-1)], 1u); atomicAdd(&acc[p0.y & (BSZ-1)], 1u);
        atomicAdd(&acc[p0.z & (BSZ-1)], 1u); atomicAdd(&acc[p0.w & (BSZ-1)], 1u);
        atomicAdd(&acc[p1.x & (BSZ-1)], 1u); atomicAdd(&acc[p1.y & (BSZ-1)], 1u);
        atomicAdd(&acc[p1.z & (BSZ-1)], 1u); atomicAdd(&acc[p1.w & (BSZ-1)], 1u);
        atomicAdd(&acc[p2.x & (BSZ-1)], 1u); atomicAdd(&acc[p2.y & (BSZ-1)], 1u);
        atomicAdd(&acc[p2.z & (BSZ-1)], 1u); atomicAdd(&acc[p2.w & (BSZ-1)], 1u);
        atomicAdd(&acc[p3.x & (BSZ-1)], 1u); atomicAdd(&acc[p3.y & (BSZ-1)], 1u);
        atomicAdd(&acc[p3.z & (BSZ-1)], 1u); atomicAdd(&acc[p3.w & (BSZ-1)], 1u);
    }
    for (unsigned i = base; i < i1; ++i) atomicAdd(&acc[eb[i] & (BSZ-1)], 1u);
    __syncthreads();
    unsigned* p = part + (size_t)blockIdx.x * BSZ;
    for (int j = threadIdx.x; j < BSZ; j += ABLK) p[j] = acc[j];
}

__global__ void r0_kernel(const unsigned* __restrict__ part, const float* __restrict__ x,
                          float* __restrict__ dinv, float* __restrict__ xd, int N) {
    int i = blockIdx.x * blockDim.x + threadIdx.x;
    if (i >= N) return;
    int b = i >> BSHIFT, dl = i & (BSZ - 1);
    unsigned deg = 0;
    const unsigned* p = part + (size_t)(b * R1REP) * BSZ + dl;
#pragma unroll
    for (int r = 0; r < R1REP; ++r) deg += p[(size_t)r * BSZ];
    float di = rsqrtf((float)deg + 1.0f);
    dinv[i] = di;
    xd[i] = di * x[i];
}

// agg1: i32 fixed-point LDS atomics
__global__ __launch_bounds__(ABLK) void b1_agg1_kernel(
        const unsigned* __restrict__ ebuf, const unsigned* __restrict__ cursors,
        const float* __restrict__ xd, int* __restrict__ part) {
    __shared__ int acc[BSZ];                    // 32 KB
    int b = blockIdx.x / R1REP, r = blockIdx.x % R1REP;
    for (int j = threadIdx.x; j < BSZ; j += ABLK) acc[j] = 0;
    __syncthreads();
    unsigned c = cursors[b]; if (c > (unsigned)CAP) c = CAP;
    unsigned per = (((c + R1REP - 1) / R1REP) + 15u) & ~15u;
    unsigned i0 = r * per, i1 = i0 + per; if (i1 > c) i1 = c;
    const unsigned* eb = ebuf + (size_t)b * CAP;
    unsigned base = i0 + threadIdx.x * 16;
    for (; base + 16 <= i1; base += ABLK * 16) {
        uv4 p0 = ntload_u4(eb + base);
        uv4 p1 = ntload_u4(eb + base + 4);
        uv4 p2 = ntload_u4(eb + base + 8);
        uv4 p3 = ntload_u4(eb + base + 12);
        int q0  = __float2int_rn(xd[p0.x >> BSHIFT] * FXS);
        int q1  = __float2int_rn(xd[p0.y >> BSHIFT] * FXS);
        int q2  = __float2int_rn(xd[p0.z >> BSHIFT] * FXS);
        int q3  = __float2int_rn(xd[p0.w >> BSHIFT] * FXS);
        int q4  = __float2int_rn(xd[p1.x >> BSHIFT] * FXS);
        int q5  = __float2int_rn(xd[p1.y >> BSHIFT] * FXS);
        int q6  = __float2int_rn(xd[p1.z >> BSHIFT] * FXS);
        int q7  = __float2int_rn(xd[p1.w >> BSHIFT] * FXS);
        int q8  = __float2int_rn(xd[p2.x >> BSHIFT] * FXS);
        int q9  = __float2int_rn(xd[p2.y >> BSHIFT] * FXS);
        int q10 = __float2int_rn(xd[p2.z >> BSHIFT] * FXS);
        int q11 = __float2int_rn(xd[p2.w >> BSHIFT] * FXS);
        int q12 = __float2int_rn(xd[p3.x >> BSHIFT] * FXS);
        int q13 = __float2int_rn(xd[p3.y >> BSHIFT] * FXS);
        int q14 = __float2int_rn(xd[p3.z >> BSHIFT] * FXS);
        int q15 = __float2int_rn(xd[p3.w >> BSHIFT] * FXS);
        atomicAdd(&acc[p0.x & (BSZ-1)], q0);  atomicAdd(&acc[p0.y & (BSZ-1)], q1);
        atomicAdd(&acc[p0.z & (BSZ-1)], q2);  atomicAdd(&acc[p0.w & (BSZ-1)], q3);
        atomicAdd(&acc[p1.x & (BSZ-1)], q4);  atomicAdd(&acc[p1.y & (BSZ-1)], q5);
        atomicAdd(&acc[p1.z & (BSZ-1)], q6);  atomicAdd(&acc[p1.w & (BSZ-1)], q7);
        atomicAdd(&acc[p2.x & (BSZ-1)], q8);  atomicAdd(&acc[p2.y & (BSZ-1)], q9);
        atomicAdd(&acc[p2.z & (BSZ-1)], q10); atomicAdd(&acc[p2.w & (BSZ-1)], q11);
        atomicAdd(&acc[p3.x & (BSZ-1)], q12); atomicAdd(&acc[p3.y & (BSZ-1)], q13);
        atomicAdd(&acc[p3.z & (BSZ-1)], q14); atomicAdd(&acc[p3.w & (BSZ-1)], q15);
    }
    for (unsigned i = base; i < i1; ++i) {
        unsigned pk = eb[i];
        atomicAdd(&acc[pk & (BSZ-1)], __float2int_rn(xd[pk >> BSHIFT] * FXS));
    }
    __syncthreads();
    int* p = part + (size_t)blockIdx.x * BSZ;
    for (int j = threadIdx.x; j < BSZ; j += ABLK) p[j] = acc[j];
}

__global__ void r1_kernel(const int* __restrict__ part, const float* __restrict__ x,
                          const float* __restrict__ dinv,
                          const float* __restrict__ W1, const float* __restrict__ b1,
                          const float* __restrict__ W2,
                          float2* __restrict__ ttp, float* __restrict__ os0,
                          float* __restrict__ os1, int N) {
    __shared__ float sW1[32], sb1[32], sW2[64];
    int t = threadIdx.x;
    if (t < 32) { sW1[t] = W1[t]; sb1[t] = b1[t]; }
    if (t < 64) sW2[t] = W2[t];
    __syncthreads();
    int i = blockIdx.x * blockDim.x + t;
    if (i >= N) return;
    int b = i >> BSHIFT, dl = i & (BSZ - 1);
    long long Sq = 0;
    const int* p = part + (size_t)(b * R1REP) * BSZ + dl;
#pragma unroll
    for (int r = 0; r < R1REP; ++r) Sq += p[(size_t)r * BSZ];
    float S = (float)Sq * FXI;
    float di = dinv[i];
    float s1v = di * di * x[i] + di * S;
    float a0 = 0.0f, a1 = 0.0f;
#pragma unroll
    for (int j = 0; j < 32; ++j) {
        float h = fmaxf(fmaf(s1v, sW1[j], sb1[j]), 0.0f);
        a0 = fmaf(h, sW2[2 * j], a0);
        a1 = fmaf(h, sW2[2 * j + 1], a1);
    }
    ttp[i] = make_float2(di * a0, di * a1);
    os0[i] = di * di * a0;
    os1[i] = di * di * a1;
}

// agg2: one packed u64 LDS atomic per edge (bias 2^31 per addend)
__global__ __launch_bounds__(ABLK) void b2_agg2_kernel(
        const unsigned* __restrict__ ebuf, const unsigned* __restrict__ cursors,
        const float2* __restrict__ ttp, u64* __restrict__ part) {
    __shared__ u64 acc[BSZ];                    // 64 KB
    int b = blockIdx.x / R2REP, r = blockIdx.x % R2REP;
    for (int j = threadIdx.x; j < BSZ; j += ABLK) acc[j] = 0ull;
    __syncthreads();
    unsigned c = cursors[b]; if (c > (unsigned)CAP) c = CAP;
    unsigned per = (((c + R2REP - 1) / R2REP) + 15u) & ~15u;
    unsigned i0 = r * per, i1 = i0 + per; if (i1 > c) i1 = c;
    const unsigned* eb = ebuf + (size_t)b * CAP;
    unsigned base = i0 + threadIdx.x * 16;
    for (; base + 16 <= i1; base += ABLK * 16) {
        uv4 p0 = ntload_u4(eb + base);
        uv4 p1 = ntload_u4(eb + base + 4);
        uv4 p2 = ntload_u4(eb + base + 8);
        uv4 p3 = ntload_u4(eb + base + 12);
        float2 v0  = ttp[p0.x >> BSHIFT], v1  = ttp[p0.y >> BSHIFT];
        float2 v2  = ttp[p0.z >> BSHIFT], v3  = ttp[p0.w >> BSHIFT];
        float2 v4  = ttp[p1.x >> BSHIFT], v5  = ttp[p1.y >> BSHIFT];
        float2 v6  = ttp[p1.z >> BSHIFT], v7  = ttp[p1.w >> BSHIFT];
        float2 v8  = ttp[p2.x >> BSHIFT], v9  = ttp[p2.y >> BSHIFT];
        float2 v10 = ttp[p2.z >> BSHIFT], v11 = ttp[p2.w >> BSHIFT];
        float2 v12 = ttp[p3.x >> BSHIFT], v13 = ttp[p3.y >> BSHIFT];
        float2 v14 = ttp[p3.z >> BSHIFT], v15 = ttp[p3.w >> BSHIFT];
        atomicAdd(&acc[p0.x & (BSZ-1)], pack_fx(v0));
        atomicAdd(&acc[p0.y & (BSZ-1)], pack_fx(v1));
        atomicAdd(&acc[p0.z & (BSZ-1)], pack_fx(v2));
        atomicAdd(&acc[p0.w & (BSZ-1)], pack_fx(v3));
        atomicAdd(&acc[p1.x & (BSZ-1)], pack_fx(v4));
        atomicAdd(&acc[p1.y & (BSZ-1)], pack_fx(v5));
        atomicAdd(&acc[p1.z & (BSZ-1)], pack_fx(v6));
        atomicAdd(&acc[p1.w & (BSZ-1)], pack_fx(v7));
        atomicAdd(&acc[p2.x & (BSZ-1)], pack_fx(v8));
        atomicAdd(&acc[p2.y & (BSZ-1)], pack_fx(v9));
        atomicAdd(&acc[p2.z & (BSZ-1)], pack_fx(v10));
        atomicAdd(&acc[p2.w & (BSZ-1)], pack_fx(v11));
        atomicAdd(&acc[p3.x & (BSZ-1)], pack_fx(v12));
        atomicAdd(&acc[p3.y & (BSZ-1)], pack_fx(v13));
        atomicAdd(&acc[p3.z & (BSZ-1)], pack_fx(v14));
        atomicAdd(&acc[p3.w & (BSZ-1)], pack_fx(v15));
    }
    for (unsigned i = base; i < i1; ++i) {
        unsigned pk = eb[i];
        atomicAdd(&acc[pk & (BSZ-1)], pack_fx(ttp[pk >> BSHIFT]));
    }
    __syncthreads();
    u64* p = part + (size_t)blockIdx.x * BSZ;
    for (int j = threadIdx.x; j < BSZ; j += ABLK) p[j] = acc[j];
}

__global__ void r2_kernel(const u64* __restrict__ part, const float* __restrict__ dinv,
                          const float* __restrict__ os0, const float* __restrict__ os1,
                          const float* __restrict__ b2v, float2* __restrict__ out, int N) {
    int i = blockIdx.x * blockDim.x + threadIdx.x;
    if (i >= N) return;
    int b = i >> BSHIFT, dl = i & (BSZ - 1);
    u64 T = 0ull;
    const u64* p = part + (size_t)(b * R2REP) * BSZ + dl;
#pragma unroll
    for (int r = 0; r < R2REP; ++r) T += p[(size_t)r * BSZ];
    float di = dinv[i];
    // recover in-degree: dinv = rsqrt(deg+1) -> deg = round(1/di^2) - 1
    long long cnt = (long long)(int)roundf(1.0f / (di * di)) - 1;
    unsigned low = (unsigned)T;
    unsigned lowbase = (unsigned)((u64)cnt << 31);
    int s0 = (int)(low - lowbase);
    long long Lfull = (cnt << 31) + (long long)s0;
    long long carry = (Lfull - (long long)(u64)low) >> 32;
    unsigned high = (unsigned)(T >> 32);
    int s1 = (int)(high - (unsigned)carry);
    float z0 = di * ((float)s0 * FXI) + os0[i] + b2v[0];
    float z1 = di * ((float)s1 * FXI) + os1[i] + b2v[1];
    float m = fmaxf(z0, z1), mn = fminf(z0, z1);
    float l = m + logf(1.0f + __expf(mn - m));
    out[i] = make_float2(z0 - l, z1 - l);
}

// ---------------- fallback (round-2 verified) ----------------

__global__ void deg_kernel(const int* __restrict__ dst, float* __restrict__ deg, int E) {
    int e = blockIdx.x * blockDim.x + threadIdx.x;
    if (e < E) atomicAdd(&deg[dst[e]], 1.0f);
}

__global__ void dinv_kernel(const float* __restrict__ deg, const float* __restrict__ x,
                            float* __restrict__ dinv, float* __restrict__ s1, int N) {
    int i = blockIdx.x * blockDim.x + threadIdx.x;
    if (i < N) {
        float di = rsqrtf(deg[i] + 1.0f);
        dinv[i] = di;
        s1[i] = di * di * x[i];
    }
}

__global__ void agg1_kernel(const int* __restrict__ src, const int* __restrict__ dst,
                            const float* __restrict__ x, const float* __restrict__ dinv,
                            float* __restrict__ s1, int E) {
    int e = blockIdx.x * blockDim.x + threadIdx.x;
    if (e < E) {
        int s = src[e], d = dst[e];
        atomicAdd(&s1[d], dinv[s] * dinv[d] * x[s]);
    }
}

__global__ void node_mlp_kernel(const float* __restrict__ s1, const float* __restrict__ dinv,
                                const float* __restrict__ W1, const float* __restrict__ b1,
                                const float* __restrict__ W2,
                                float* __restrict__ t0, float* __restrict__ t1,
                                float* __restrict__ o0, float* __restrict__ o1, int N) {
    __shared__ float sW1[32], sb1[32], sW2[64];
    int t = threadIdx.x;
    if (t < 32) { sW1[t] = W1[t]; sb1[t] = b1[t]; }
    if (t < 64) sW2[t] = W2[t];
    __syncthreads();
    int i = blockIdx.x * blockDim.x + t;
    if (i < N) {
        float s = s1[i];
        float a0 = 0.0f, a1 = 0.0f;
#pragma unroll
        for (int j = 0; j < 32; ++j) {
            float h = fmaxf(fmaf(s, sW1[j], sb1[j]), 0.0f);
            a0 = fmaf(h, sW2[2 * j], a0);
            a1 = fmaf(h, sW2[2 * j + 1], a1);
        }
        t0[i] = a0; t1[i] = a1;
        float d2 = dinv[i] * dinv[i];
        o0[i] = d2 * a0; o1[i] = d2 * a1;
    }
}

__global__ void agg2_kernel(const int* __restrict__ src, const int* __restrict__ dst,
                            const float* __restrict__ dinv,
                            const float* __restrict__ t0, const float* __restrict__ t1,
                            float* __restrict__ o0, float* __restrict__ o1, int E) {
    int e = blockIdx.x * blockDim.x + threadIdx.x;
    if (e < E) {
        int s = src[e], d = dst[e];
        float w = dinv[s] * dinv[d];
        atomicAdd(&o0[d], w * t0[s]);
        atomicAdd(&o1[d], w * t1[s]);
    }
}

__global__ void logsoftmax_kernel(const float* __restrict__ o0, const float* __restrict__ o1,
                                  const float* __restrict__ b2, float* __restrict__ out, int N) {
    int i = blockIdx.x * blockDim.x + threadIdx.x;
    if (i < N) {
        float z0 = o0[i] + b2[0];
        float z1 = o1[i] + b2[1];
        float m = fmaxf(z0, z1), mn = fminf(z0, z1);
        float l = m + logf(1.0f + __expf(mn - m));
        ((float2*)out)[i] = make_float2(z0 - l, z1 - l);
    }
}

// ---------------- launch ----------------

extern "C" void kernel_launch(void* const* d_in, const int* in_sizes, int n_in,
                              void* d_out, int out_size, void* d_ws, size_t ws_size,
                              hipStream_t stream) {
    const float* x  = (const float*)d_in[0];
    const int* ei   = (const int*)d_in[1];     // int32 (JAX x64 disabled)
    const float* W1 = (const float*)d_in[2];
    const float* b1 = (const float*)d_in[3];
    const float* W2 = (const float*)d_in[4];
    const float* b2 = (const float*)d_in[5];
    float* out = (float*)d_out;

    const int N = in_sizes[0];
    const int E = in_sizes[1] / 2;
    const int* src = ei;
    const int* dst = ei + E;

    // fast-path ws layout (bytes) -- identical to R4..R10 (proven fit;
    // fill counter shows ws_size = 268 MB, ample slack).
    const size_t OFF_CUR  = 0;                                    // 64 u32
    const size_t OFF_EBUF = 256;
    const size_t SZ_EBUF  = (size_t)NBK * CAP * 4;                // 28.1 MB
    const size_t OFF_PART = OFF_EBUF + SZ_EBUF;
    const size_t SZ_PART  = (size_t)NBK * 40 * BSZ * 4;           // 17.0 MB (legacy size)
    const size_t OFF_NODE = OFF_PART + SZ_PART;
    const size_t SZ_NODE  = (size_t)N * 4;
    const size_t NEED = OFF_NODE + 6 * SZ_NODE + 256;

    bool fast = (ws_size >= NEED) && (N <= NBK * BSZ) && (N < (1 << 17)) && N > 0 &&
                ((size_t)E * BSZ / (size_t)N + 16384 <= (size_t)CAP);

    if (fast) {
        unsigned* cursors = (unsigned*)((char*)d_ws + OFF_CUR);
        unsigned* ebuf    = (unsigned*)((char*)d_ws + OFF_EBUF);
        int*      part    = (int*)((char*)d_ws + OFF_PART);
        float*    dinv    = (float*)((char*)d_ws + OFF_NODE);
        float*    xd      = dinv + N;
        float*    os0     = xd + N;
        float*    os1     = os0 + N;
        float2*   ttp     = (float2*)(os1 + N);                   // 2N floats

        (void)hipMemsetAsync(cursors, 0, 256, stream);

        int ng = (N + 255) / 256;

        bucketize_kernel<<<BGRID, BBLK, 0, stream>>>(src, dst, cursors, ebuf, E);
        b0_deg_kernel<<<NBK * R1REP, ABLK, 0, stream>>>(ebuf, cursors, (unsigned*)part);
        r0_kernel<<<ng, 256, 0, stream>>>((unsigned*)part, x, dinv, xd, N);
        b1_agg1_kernel<<<NBK * R1REP, ABLK, 0, stream>>>(ebuf, cursors, xd, part);
        r1_kernel<<<ng, 256, 0, stream>>>(part, x, dinv, W1, b1, W2, ttp, os0, os1, N);
        b2_agg2_kernel<<<NBK * R2REP, ABLK, 0, stream>>>(ebuf, cursors, ttp, (u64*)part);
        r2_kernel<<<ng, 256, 0, stream>>>((const u64*)part, dinv, os0, os1, b2, (float2*)out, N);
    } else {
        float* deg  = (float*)d_ws;
        float* dinv = deg + N;
        float* s1   = dinv + N;
        float* t0   = s1 + N;
        float* t1   = t0 + N;
        float* o0   = t1 + N;
        float* o1   = o0 + N;

        (void)hipMemsetAsync(deg, 0, (size_t)N * sizeof(float), stream);
        int eg = (E + 255) / 256, ng = (N + 255) / 256;
        deg_kernel<<<eg, 256, 0, stream>>>(dst, deg, E);
        dinv_kernel<<<ng, 256, 0, stream>>>(deg, x, dinv, s1, N);
        agg1_kernel<<<eg, 256, 0, stream>>>(src, dst, x, dinv, s1, E);
        node_mlp_kernel<<<ng, 256, 0, stream>>>(s1, dinv, W1, b1, W2, t0, t1, o0, o1, N);
        agg2_kernel<<<eg, 256, 0, stream>>>(src, dst, dinv, t0, t1, o0, o1, E);
        logsoftmax_kernel<<<ng, 256, 0, stream>>>(o0, o1, b2, out, N);
    }
}